// Round 1
// baseline (1816.479 us; speedup 1.0000x reference)
//
#include <hip/hip_runtime.h>
#include <math.h>

// Problem constants
#define BB 8
#define TT 64          // pyramid length
#define TFL 256        // frame_level length
#define PC 512
#define CAT_C 3572
#define GROUPS 32

// ---------------------------------------------------------------------------
// Pointwise conv (1x1): Y[b,o,t] = bias[o] + sum_c W[o,c] * X[b,c,t]
// X: [B, C, 64] contiguous. Y: [B, O, 64] contiguous.
// block (64 t, 4 oi); each thread computes 4 o rows -> o-tile of 16.
// grid (O/16, B)
// ---------------------------------------------------------------------------
__global__ __launch_bounds__(256) void pw_gemm_kernel(
    const float* __restrict__ X, const float* __restrict__ W,
    const float* __restrict__ bias, float* __restrict__ Y, int C, int O) {
  __shared__ float ldsX[32 * 64];
  const int t = threadIdx.x;    // 0..63
  const int oi = threadIdx.y;   // 0..3
  const int b = blockIdx.y;
  const int o0 = blockIdx.x * 16;
  const int tid = oi * 64 + t;
  float acc[4] = {0.f, 0.f, 0.f, 0.f};
  const float* xb = X + (size_t)b * C * 64;
  for (int c0 = 0; c0 < C; c0 += 32) {
    const int cn = min(32, C - c0);
    const int ne = cn * 64;
    __syncthreads();
    for (int e = tid; e < ne; e += 256) ldsX[e] = xb[c0 * 64 + e];
    __syncthreads();
    for (int cc = 0; cc < cn; cc++) {
      const float xv = ldsX[cc * 64 + t];
      const int c = c0 + cc;
#pragma unroll
      for (int r = 0; r < 4; r++) {
        const int o = o0 + oi * 4 + r;
        acc[r] += W[(size_t)o * C + c] * xv;
      }
    }
  }
#pragma unroll
  for (int r = 0; r < 4; r++) {
    const int o = o0 + oi * 4 + r;
    Y[((size_t)b * O + o) * 64 + t] = acc[r] + bias[o];
  }
}

// ---------------------------------------------------------------------------
// GroupNorm(32) + ReLU over [B, C, 64]; writes into a channel slice of an
// output tensor with channel-count outCS at channel offset chOff.
// grid (B*32), block 256.
// ---------------------------------------------------------------------------
__global__ __launch_bounds__(256) void gn_relu_kernel(
    const float* __restrict__ X, const float* __restrict__ gamma,
    const float* __restrict__ beta, float* __restrict__ Y, int C, int outCS,
    int chOff) {
  const int b = blockIdx.x / GROUPS;
  const int g = blockIdx.x % GROUPS;
  const int cpg = C / GROUPS;
  const int N = cpg * 64;
  const float* xg = X + ((size_t)b * C + g * cpg) * 64;
  float s = 0.f, ss = 0.f;
  for (int e = threadIdx.x; e < N; e += 256) {
    const float v = xg[e];
    s += v;
    ss += v * v;
  }
#pragma unroll
  for (int off = 32; off > 0; off >>= 1) {
    s += __shfl_down(s, off);
    ss += __shfl_down(ss, off);
  }
  __shared__ float rs[4], rss[4];
  const int wave = threadIdx.x >> 6;
  const int lane = threadIdx.x & 63;
  if (lane == 0) { rs[wave] = s; rss[wave] = ss; }
  __syncthreads();
  if (threadIdx.x == 0) {
    float ts = 0.f, tss = 0.f;
    for (int w = 0; w < 4; w++) { ts += rs[w]; tss += rss[w]; }
    rs[0] = ts; rss[0] = tss;
  }
  __syncthreads();
  const float mean = rs[0] / (float)N;
  const float var = rss[0] / (float)N - mean * mean;
  const float rstd = rsqrtf(var + 1e-5f);
  for (int e = threadIdx.x; e < N; e += 256) {
    const int c = g * cpg + (e >> 6);
    float v = (xg[e] - mean) * rstd * gamma[c] + beta[c];
    v = fmaxf(v, 0.f);
    Y[((size_t)b * outCS + chOff + c) * 64 + (e & 63)] = v;
  }
}

// ---------------------------------------------------------------------------
// BoundaryMaxPooling: F [B,C,L], segs [B,64,4] -> Y slice [B,C,64]
// first C/2 channels use segs[0:2], second half segs[2:4] (inclusive ranges).
// grid (64 t, B), block 256 over channels.
// ---------------------------------------------------------------------------
__global__ __launch_bounds__(256) void bmp_kernel(
    const float* __restrict__ F, const int* __restrict__ segs,
    float* __restrict__ Y, int C, int L, int outCS, int chOff) {
  const int t = blockIdx.x;
  const int b = blockIdx.y;
  const int* sg = segs + ((size_t)b * 64 + t) * 4;
  const int s0 = min(max(sg[0], 0), L - 1);
  const int e0 = max(min(max(sg[1], 0), L - 1), s0);
  const int s1 = min(max(sg[2], 0), L - 1);
  const int e1 = max(min(max(sg[3], 0), L - 1), s1);
  const int C2 = C >> 1;
  for (int c = threadIdx.x; c < C; c += 256) {
    const int s = (c < C2) ? s0 : s1;
    const int e = (c < C2) ? e0 : e1;
    const float* row = F + ((size_t)b * C + c) * L;
    float m = -INFINITY;
    for (int l = s; l <= e; l++) m = fmaxf(m, row[l]);
    Y[((size_t)b * outCS + chOff + c) * 64 + t] = m;
  }
}

// ---------------------------------------------------------------------------
// Anchor-gather + valid-conv:
// Y[b,o,t] = bias[o] + valid(b,t) * sum_{c,k} F[b,c,idx(b,t,k)] * W[o,c,k]
// idx = clip(left + (k*seglen)/K, 0, L-1); left/right = clip(anchor, 0, L);
// valid = right > left; seglen = right+1-left.
// block (64 t, 4 oi) each thread 4 o rows -> o-tile 16. grid (O/16, B).
// ---------------------------------------------------------------------------
template <int K, int L>
__global__ __launch_bounds__(256) void anchor_conv_kernel(
    const float* __restrict__ F, const int* __restrict__ anc,
    const float* __restrict__ W, const float* __restrict__ bias,
    float* __restrict__ Y, int Cin, int outCS, int chOff) {
  __shared__ int sidx[64 * K];
  __shared__ float svalid[64];
  __shared__ float ldsF[2048];
  const int t = threadIdx.x;
  const int oi = threadIdx.y;
  const int b = blockIdx.y;
  const int o0 = blockIdx.x * 16;
  const int tid = oi * 64 + t;

  for (int e = tid; e < 64 * K; e += 256) {
    const int tt = e / K, k = e % K;
    const int a0 = anc[((size_t)b * 64 + tt) * 2 + 0];
    const int a1 = anc[((size_t)b * 64 + tt) * 2 + 1];
    const int left = min(max(a0, 0), L);
    const int right = min(max(a1, 0), L);
    const int seglen = right + 1 - left;
    int ix = left + (k * seglen) / K;
    ix = min(max(ix, 0), L - 1);
    sidx[e] = ix;
    if (k == 0) svalid[tt] = (right > left) ? 1.f : 0.f;
  }
  __syncthreads();

  float acc[4] = {0.f, 0.f, 0.f, 0.f};
  const float* fb = F + (size_t)b * Cin * L;
  constexpr int CC = 2048 / L;  // rows per LDS chunk
  for (int c0 = 0; c0 < Cin; c0 += CC) {
    __syncthreads();
    for (int e = tid; e < CC * L; e += 256) ldsF[e] = fb[c0 * L + e];
    __syncthreads();
    for (int cc = 0; cc < CC; cc++) {
      float gv[K];
#pragma unroll
      for (int k = 0; k < K; k++) gv[k] = ldsF[cc * L + sidx[t * K + k]];
      const int c = c0 + cc;
#pragma unroll
      for (int r = 0; r < 4; r++) {
        const int o = o0 + oi * 4 + r;
        const float* wr = W + ((size_t)o * Cin + c) * K;
        float a = 0.f;
#pragma unroll
        for (int k = 0; k < K; k++) a += gv[k] * wr[k];
        acc[r] += a;
      }
    }
  }
  const float v = svalid[t];
#pragma unroll
  for (int r = 0; r < 4; r++) {
    const int o = o0 + oi * 4 + r;
    Y[((size_t)b * outCS + chOff + o) * 64 + t] = acc[r] * v + bias[o];
  }
}

// ---------------------------------------------------------------------------
// Copy [B,C,64] tensor into a channel slice of cat.
// ---------------------------------------------------------------------------
__global__ __launch_bounds__(256) void copy_to_cat_kernel(
    const float* __restrict__ src, float* __restrict__ cat, int C, int chOff) {
  const int i = blockIdx.x * 256 + threadIdx.x;
  const int total = BB * C * 64;
  if (i >= total) return;
  const int t = i & 63;
  const int c = (i >> 6) % C;
  const int b = i / (64 * C);
  cat[((size_t)b * CAT_C + chOff + c) * 64 + t] = src[i];
}

extern "C" void kernel_launch(void* const* d_in, const int* in_sizes, int n_in,
                              void* d_out, int out_size, void* d_ws,
                              size_t ws_size, hipStream_t stream) {
  const float* feature      = (const float*)d_in[0];   // [8,512,64]
  const float* frame_feat   = (const float*)d_in[1];   // [8,512,256]
  const int*   segments     = (const int*)d_in[2];     // [8,64,4]
  const int*   frame_segs   = (const int*)d_in[3];     // [8,64,4]
  const float* feat_lastcls = (const float*)d_in[4];   // [8,498,64]
  const int*   anchor       = (const int*)d_in[5];     // [8,64,2]
  const int*   frame_anchor = (const int*)d_in[6];     // [8,64,2]
  // d_in[7] = order (always 0)
  const float* locres       = (const float*)d_in[8];   // [8,2,64]
  const float* w_cur  = (const float*)d_in[9];
  const float* b_cur  = (const float*)d_in[10];
  const float* g_cur  = (const float*)d_in[11];
  const float* be_cur = (const float*)d_in[12];
  const float* w_lr   = (const float*)d_in[13];
  const float* b_lr   = (const float*)d_in[14];
  const float* g_lr   = (const float*)d_in[15];
  const float* be_lr  = (const float*)d_in[16];
  const float* w_roi  = (const float*)d_in[17];
  const float* b_roi  = (const float*)d_in[18];
  const float* g_roi  = (const float*)d_in[19];
  const float* be_roi = (const float*)d_in[20];
  const float* w_cp   = (const float*)d_in[21];  // [512,1024,16]
  const float* b_cp   = (const float*)d_in[22];
  const float* w_cp0  = (const float*)d_in[23];  // [512,512,8]
  const float* b_cp0  = (const float*)d_in[24];
  const float* w_prop = (const float*)d_in[25];  // [512,3572]
  const float* b_prop = (const float*)d_in[26];
  const float* g_prop = (const float*)d_in[27];
  const float* be_prop= (const float*)d_in[28];

  float* out_main = (float*)d_out;                 // [8,512,64]
  float* feat_lr  = (float*)d_out + BB * PC * 64;  // [8,1024,64]

  // workspace layout (floats)
  float* cat  = (float*)d_ws;                       // [8,3572,64]
  float* tmpA = cat + (size_t)BB * CAT_C * 64;      // up to [8,1024,64]
  float* tmpB = tmpA + (size_t)BB * 1024 * 64;      // up to [8,1024,64]

  const dim3 blk(64, 4, 1);

  // 1. y_cur = c1(feature, w_cur) -> tmpA ; GN+ReLU -> cat[1536:2048]
  pw_gemm_kernel<<<dim3(512 / 16, BB), blk, 0, stream>>>(feature, w_cur, b_cur, tmpA, 512, 512);
  gn_relu_kernel<<<BB * GROUPS, 256, 0, stream>>>(tmpA, g_cur, be_cur, cat, 512, CAT_C, 1536);

  // 2. y_lr = c1(feature, w_lr) -> tmpB ; GN+ReLU -> feat_lr (output #2)
  pw_gemm_kernel<<<dim3(1024 / 16, BB), blk, 0, stream>>>(feature, w_lr, b_lr, tmpB, 512, 1024);
  gn_relu_kernel<<<BB * GROUPS, 256, 0, stream>>>(tmpB, g_lr, be_lr, feat_lr, 1024, 1024, 0);

  // 3. prop_feature = bmp(feat_lr, segments) -> cat[512:1536]
  bmp_kernel<<<dim3(64, BB), 256, 0, stream>>>(feat_lr, segments, cat, 1024, 64, CAT_C, 512);

  // 4. prop_roi = relu(gn(c1(bmp(frame_feat, frame_segs), w_roi))) -> cat[0:512]
  bmp_kernel<<<dim3(64, BB), 256, 0, stream>>>(frame_feat, frame_segs, tmpA, 512, 256, 512, 0);
  pw_gemm_kernel<<<dim3(512 / 16, BB), blk, 0, stream>>>(tmpA, w_roi, b_roi, tmpB, 512, 512);
  gn_relu_kernel<<<BB * GROUPS, 256, 0, stream>>>(tmpB, g_roi, be_roi, cat, 512, CAT_C, 0);

  // 5. con_feature = anchor conv on feat_lr (K=16, Cin=1024, L=64) -> cat[2546:3058]
  anchor_conv_kernel<16, 64><<<dim3(512 / 16, BB), blk, 0, stream>>>(
      feat_lr, anchor, w_cp, b_cp, cat, 1024, CAT_C, 2546);

  // 6. frame_con = anchor conv on frame_feat (K=8, Cin=512, L=256) -> tmpA
  anchor_conv_kernel<8, 256><<<dim3(512 / 16, BB), blk, 0, stream>>>(
      frame_feat, frame_anchor, w_cp0, b_cp0, tmpA, 512, 512, 0);
  //    prop_con = relu(gn(c1(frame_con, w_roi))) -> cat[3058:3570]
  pw_gemm_kernel<<<dim3(512 / 16, BB), blk, 0, stream>>>(tmpA, w_roi, b_roi, tmpB, 512, 512);
  gn_relu_kernel<<<BB * GROUPS, 256, 0, stream>>>(tmpB, g_roi, be_roi, cat, 512, CAT_C, 3058);

  // 7. copies: feature_lastclass -> cat[2048:2546], LocResult -> cat[3570:3572]
  copy_to_cat_kernel<<<(BB * 498 * 64 + 255) / 256, 256, 0, stream>>>(feat_lastcls, cat, 498, 2048);
  copy_to_cat_kernel<<<(BB * 2 * 64 + 255) / 256, 256, 0, stream>>>(locres, cat, 2, 3570);

  // 8. out = relu(gn(c1(cat, w_prop))) -> out_main
  pw_gemm_kernel<<<dim3(512 / 16, BB), blk, 0, stream>>>(cat, w_prop, b_prop, tmpA, CAT_C, 512);
  gn_relu_kernel<<<BB * GROUPS, 256, 0, stream>>>(tmpA, g_prop, be_prop, out_main, 512, 512, 0);
}

// Round 2
// 885.703 us; speedup vs baseline: 2.0509x; 2.0509x over previous
//
#include <hip/hip_runtime.h>
#include <math.h>

// Problem constants
#define BB 8
#define CAT_C 3572
#define GROUPS 32

typedef __attribute__((ext_vector_type(8))) short short8;
typedef __attribute__((ext_vector_type(4))) float f32x4;

__device__ inline ushort f2bf(float f) {
  union { float f; unsigned u; } x;
  x.f = f;
  return (ushort)((x.u + 0x7FFFu + ((x.u >> 16) & 1u)) >> 16);
}

// ---------------------------------------------------------------------------
// Pointwise conv (1x1): Y[b,o,t] = bias[o] + sum_c W[o,c] * X[b,c,t]
// ---------------------------------------------------------------------------
__global__ __launch_bounds__(256) void pw_gemm_kernel(
    const float* __restrict__ X, const float* __restrict__ W,
    const float* __restrict__ bias, float* __restrict__ Y, int C, int O) {
  __shared__ float ldsX[32 * 64];
  const int t = threadIdx.x;
  const int oi = threadIdx.y;
  const int b = blockIdx.y;
  const int o0 = blockIdx.x * 16;
  const int tid = oi * 64 + t;
  float acc[4] = {0.f, 0.f, 0.f, 0.f};
  const float* xb = X + (size_t)b * C * 64;
  for (int c0 = 0; c0 < C; c0 += 32) {
    const int cn = min(32, C - c0);
    const int ne = cn * 64;
    __syncthreads();
    for (int e = tid; e < ne; e += 256) ldsX[e] = xb[c0 * 64 + e];
    __syncthreads();
    for (int cc = 0; cc < cn; cc++) {
      const float xv = ldsX[cc * 64 + t];
      const int c = c0 + cc;
#pragma unroll
      for (int r = 0; r < 4; r++) {
        const int o = o0 + oi * 4 + r;
        acc[r] += W[(size_t)o * C + c] * xv;
      }
    }
  }
#pragma unroll
  for (int r = 0; r < 4; r++) {
    const int o = o0 + oi * 4 + r;
    Y[((size_t)b * O + o) * 64 + t] = acc[r] + bias[o];
  }
}

// ---------------------------------------------------------------------------
// GroupNorm(32) + ReLU over [B, C, 64] -> channel slice of output tensor
// ---------------------------------------------------------------------------
__global__ __launch_bounds__(256) void gn_relu_kernel(
    const float* __restrict__ X, const float* __restrict__ gamma,
    const float* __restrict__ beta, float* __restrict__ Y, int C, int outCS,
    int chOff) {
  const int b = blockIdx.x / GROUPS;
  const int g = blockIdx.x % GROUPS;
  const int cpg = C / GROUPS;
  const int N = cpg * 64;
  const float* xg = X + ((size_t)b * C + g * cpg) * 64;
  float s = 0.f, ss = 0.f;
  for (int e = threadIdx.x; e < N; e += 256) {
    const float v = xg[e];
    s += v;
    ss += v * v;
  }
#pragma unroll
  for (int off = 32; off > 0; off >>= 1) {
    s += __shfl_down(s, off);
    ss += __shfl_down(ss, off);
  }
  __shared__ float rs[4], rss[4];
  const int wave = threadIdx.x >> 6;
  const int lane = threadIdx.x & 63;
  if (lane == 0) { rs[wave] = s; rss[wave] = ss; }
  __syncthreads();
  if (threadIdx.x == 0) {
    float ts = 0.f, tss = 0.f;
    for (int w = 0; w < 4; w++) { ts += rs[w]; tss += rss[w]; }
    rs[0] = ts; rss[0] = tss;
  }
  __syncthreads();
  const float mean = rs[0] / (float)N;
  const float var = rss[0] / (float)N - mean * mean;
  const float rstd = rsqrtf(var + 1e-5f);
  for (int e = threadIdx.x; e < N; e += 256) {
    const int c = g * cpg + (e >> 6);
    float v = (xg[e] - mean) * rstd * gamma[c] + beta[c];
    v = fmaxf(v, 0.f);
    Y[((size_t)b * outCS + chOff + c) * 64 + (e & 63)] = v;
  }
}

// ---------------------------------------------------------------------------
// BoundaryMaxPooling
// ---------------------------------------------------------------------------
__global__ __launch_bounds__(256) void bmp_kernel(
    const float* __restrict__ F, const int* __restrict__ segs,
    float* __restrict__ Y, int C, int L, int outCS, int chOff) {
  const int t = blockIdx.x;
  const int b = blockIdx.y;
  const int* sg = segs + ((size_t)b * 64 + t) * 4;
  const int s0 = min(max(sg[0], 0), L - 1);
  const int e0 = max(min(max(sg[1], 0), L - 1), s0);
  const int s1 = min(max(sg[2], 0), L - 1);
  const int e1 = max(min(max(sg[3], 0), L - 1), s1);
  const int C2 = C >> 1;
  for (int c = threadIdx.x; c < C; c += 256) {
    const int s = (c < C2) ? s0 : s1;
    const int e = (c < C2) ? e0 : e1;
    const float* row = F + ((size_t)b * C + c) * L;
    float m = -INFINITY;
    for (int l = s; l <= e; l++) m = fmaxf(m, row[l]);
    Y[((size_t)b * outCS + chOff + c) * 64 + t] = m;
  }
}

// ---------------------------------------------------------------------------
// f32 -> bf16 elementwise convert (vectorized 4-wide)
// ---------------------------------------------------------------------------
__global__ __launch_bounds__(256) void cvt_bf16_kernel(
    const float4* __restrict__ X, uint2* __restrict__ Y, int n4) {
  const int i = blockIdx.x * 256 + threadIdx.x;
  if (i >= n4) return;
  const float4 v = X[i];
  uint2 o;
  o.x = (unsigned)f2bf(v.x) | ((unsigned)f2bf(v.y) << 16);
  o.y = (unsigned)f2bf(v.z) | ((unsigned)f2bf(v.w) << 16);
  Y[i] = o;
}

// ---------------------------------------------------------------------------
// Anchor gather: G[b][t][c*K+k] = bf16(F[b][c][idx(b,t,k)])
// (validity handled later in the reduce epilogue; conv is linear)
// grid (Cin/CC, B), block 256.
// ---------------------------------------------------------------------------
template <int K, int L, int CC, int Cin>
__global__ __launch_bounds__(256) void gather_kernel(
    const float* __restrict__ F, const int* __restrict__ anc,
    ushort* __restrict__ G) {
  __shared__ float Fl[CC * L];
  __shared__ int sidx[64 * K];
  const int c0 = blockIdx.x * CC;
  const int b = blockIdx.y;
  const int tid = threadIdx.x;
  for (int e = tid; e < 64 * K; e += 256) {
    const int tt = e / K, k = e % K;
    const int a0 = anc[((size_t)b * 64 + tt) * 2 + 0];
    const int a1 = anc[((size_t)b * 64 + tt) * 2 + 1];
    const int left = min(max(a0, 0), L);
    const int right = min(max(a1, 0), L);
    const int seglen = right + 1 - left;
    sidx[e] = min(max(left + (k * seglen) / K, 0), L - 1);
  }
  const float* Fb = F + ((size_t)b * Cin + c0) * L;
  for (int e = tid; e < CC * L; e += 256) Fl[e] = Fb[e];
  __syncthreads();
  constexpr int KK = Cin * K;
  constexpr int PH = (CC * K) / 2;  // bf16 pairs per t
  for (int f = tid; f < 64 * PH; f += 256) {
    const int t = f / PH;
    const int p = f % PH;
    const int col0 = 2 * p;
    const int cc = col0 / K;
    const int k = col0 % K;
    const float v0 = Fl[cc * L + sidx[t * K + k]];
    const float v1 = Fl[cc * L + sidx[t * K + k + 1]];
    const unsigned pk = (unsigned)f2bf(v0) | ((unsigned)f2bf(v1) << 16);
    *(unsigned*)(G + (size_t)(b * 64 + t) * KK + c0 * K + col0) = pk;
  }
}

// ---------------------------------------------------------------------------
// MFMA GEMM: P[kz][b][n][m] = sum_{k in block-slice} G[b][m][k] * Wb[n][k]
// G: [8][64][KK] bf16, Wb: [512][KK] bf16. Block: 256 thr = 4 waves, each
// wave one k-quarter of the block k-span, wave tile M64 x N64 via 4x4 MFMA
// 16x16x32 tiles. Cross-wave reduce in LDS, write f32 partial.
// grid (N/64=8, B=8, ks).
// ---------------------------------------------------------------------------
__global__ __launch_bounds__(256) void anchor_mfma_kernel(
    const ushort* __restrict__ G, const ushort* __restrict__ Wb,
    float* __restrict__ P, int KK, int kspan) {
  const int n0 = blockIdx.x * 64;
  const int b = blockIdx.y;
  const int kz = blockIdx.z;
  const int w = threadIdx.x >> 6;
  const int lane = threadIdx.x & 63;
  const int l15 = lane & 15, l4 = lane >> 4;
  const int wk = kspan >> 2;
  const int kbeg = kz * kspan + w * wk;
  const int kend = kbeg + wk;

  f32x4 acc[4][4] = {};
  const ushort* ap[4];
  const ushort* bp[4];
#pragma unroll
  for (int i = 0; i < 4; i++)
    ap[i] = G + ((size_t)b * 64 + i * 16 + l15) * KK + l4 * 8;
#pragma unroll
  for (int j = 0; j < 4; j++)
    bp[j] = Wb + (size_t)(n0 + j * 16 + l15) * KK + l4 * 8;

  for (int k = kbeg; k < kend; k += 32) {
    short8 a[4], bb[4];
#pragma unroll
    for (int i = 0; i < 4; i++) a[i] = *(const short8*)(ap[i] + k);
#pragma unroll
    for (int j = 0; j < 4; j++) bb[j] = *(const short8*)(bp[j] + k);
#pragma unroll
    for (int i = 0; i < 4; i++)
#pragma unroll
      for (int j = 0; j < 4; j++)
        acc[i][j] = __builtin_amdgcn_mfma_f32_16x16x32_bf16(a[i], bb[j],
                                                            acc[i][j], 0, 0, 0);
  }

  // cross-wave reduction: red[m][n] with padded stride 65
  __shared__ float red[64 * 65];
  for (int ww = 0; ww < 4; ww++) {
    __syncthreads();
    if (w == ww) {
#pragma unroll
      for (int i = 0; i < 4; i++)
#pragma unroll
        for (int j = 0; j < 4; j++)
#pragma unroll
          for (int r = 0; r < 4; r++) {
            const int m = i * 16 + l4 * 4 + r;
            const int n = j * 16 + l15;
            if (ww == 0)
              red[m * 65 + n] = acc[i][j][r];
            else
              red[m * 65 + n] += acc[i][j][r];
          }
    }
  }
  __syncthreads();
  float* Pp = P + (((size_t)kz * BB + b) * 512 + n0) * 64;
  for (int e = threadIdx.x; e < 4096; e += 256) {
    const int n = e >> 6, m = e & 63;
    Pp[e] = red[m * 65 + n];
  }
}

// ---------------------------------------------------------------------------
// Split-K reduce + valid mask + bias -> f32 [b][outCS][64] slice
// ---------------------------------------------------------------------------
__global__ __launch_bounds__(256) void anchor_reduce_kernel(
    const float* __restrict__ P, int ks, const float* __restrict__ bias,
    const int* __restrict__ anc, int L, float* __restrict__ Y, int outCS,
    int chOff) {
  const int idx = blockIdx.x * 256 + threadIdx.x;
  if (idx >= BB * 512 * 64) return;
  const int m = idx & 63;
  const int n = (idx >> 6) & 511;
  const int b = idx >> 15;
  float s = 0.f;
  for (int z = 0; z < ks; z++) s += P[(size_t)z * BB * 512 * 64 + idx];
  const int a0 = anc[((size_t)b * 64 + m) * 2 + 0];
  const int a1 = anc[((size_t)b * 64 + m) * 2 + 1];
  const int left = min(max(a0, 0), L);
  const int right = min(max(a1, 0), L);
  const float v = (right > left) ? 1.f : 0.f;
  Y[((size_t)b * outCS + chOff + n) * 64 + m] = s * v + bias[n];
}

// ---------------------------------------------------------------------------
// Copy [B,C,64] into channel slice of cat
// ---------------------------------------------------------------------------
__global__ __launch_bounds__(256) void copy_to_cat_kernel(
    const float* __restrict__ src, float* __restrict__ cat, int C, int chOff) {
  const int i = blockIdx.x * 256 + threadIdx.x;
  const int total = BB * C * 64;
  if (i >= total) return;
  const int t = i & 63;
  const int c = (i >> 6) % C;
  const int b = i / (64 * C);
  cat[((size_t)b * CAT_C + chOff + c) * 64 + t] = src[i];
}

extern "C" void kernel_launch(void* const* d_in, const int* in_sizes, int n_in,
                              void* d_out, int out_size, void* d_ws,
                              size_t ws_size, hipStream_t stream) {
  const float* feature      = (const float*)d_in[0];
  const float* frame_feat   = (const float*)d_in[1];
  const int*   segments     = (const int*)d_in[2];
  const int*   frame_segs   = (const int*)d_in[3];
  const float* feat_lastcls = (const float*)d_in[4];
  const int*   anchor       = (const int*)d_in[5];
  const int*   frame_anchor = (const int*)d_in[6];
  const float* locres       = (const float*)d_in[8];
  const float* w_cur  = (const float*)d_in[9];
  const float* b_cur  = (const float*)d_in[10];
  const float* g_cur  = (const float*)d_in[11];
  const float* be_cur = (const float*)d_in[12];
  const float* w_lr   = (const float*)d_in[13];
  const float* b_lr   = (const float*)d_in[14];
  const float* g_lr   = (const float*)d_in[15];
  const float* be_lr  = (const float*)d_in[16];
  const float* w_roi  = (const float*)d_in[17];
  const float* b_roi  = (const float*)d_in[18];
  const float* g_roi  = (const float*)d_in[19];
  const float* be_roi = (const float*)d_in[20];
  const float* w_cp   = (const float*)d_in[21];  // [512,1024,16]
  const float* b_cp   = (const float*)d_in[22];
  const float* w_cp0  = (const float*)d_in[23];  // [512,512,8]
  const float* b_cp0  = (const float*)d_in[24];
  const float* w_prop = (const float*)d_in[25];
  const float* b_prop = (const float*)d_in[26];
  const float* g_prop = (const float*)d_in[27];
  const float* be_prop= (const float*)d_in[28];

  float* out_main = (float*)d_out;                  // [8,512,64]
  float* feat_lr  = (float*)d_out + BB * 512 * 64;  // [8,1024,64]

  // workspace layout
  float* cat  = (float*)d_ws;                 // 1,828,864 f
  float* tmpA = cat + 1828864;                // 524,288 f
  float* tmpB = tmpA + 524288;                // 524,288 f
  float* P1   = tmpB + 524288;                // 1,048,576 f  (ks=4 partials)
  float* P0   = P1 + 1048576;                 // 524,288 f    (ks=2 partials)
  ushort* G1  = (ushort*)(P0 + 524288);       // 8,388,608 bf16
  ushort* G0  = G1 + 8388608;                 // 2,097,152 bf16
  ushort* Wb1 = G0 + 2097152;                 // 8,388,608 bf16
  ushort* Wb0 = Wb1 + 8388608;                // 2,097,152 bf16
  // total ~57 MB

  const dim3 blk(64, 4, 1);

  // weight conversions (independent of activations)
  cvt_bf16_kernel<<<8192, 256, 0, stream>>>((const float4*)w_cp, (uint2*)Wb1, 2097152);
  cvt_bf16_kernel<<<2048, 256, 0, stream>>>((const float4*)w_cp0, (uint2*)Wb0, 524288);

  // 1. fm_short path -> cat[1536:2048]
  pw_gemm_kernel<<<dim3(32, BB), blk, 0, stream>>>(feature, w_cur, b_cur, tmpA, 512, 512);
  gn_relu_kernel<<<BB * GROUPS, 256, 0, stream>>>(tmpA, g_cur, be_cur, cat, 512, CAT_C, 1536);

  // 2. feat_lr (output #2)
  pw_gemm_kernel<<<dim3(64, BB), blk, 0, stream>>>(feature, w_lr, b_lr, tmpB, 512, 1024);
  gn_relu_kernel<<<BB * GROUPS, 256, 0, stream>>>(tmpB, g_lr, be_lr, feat_lr, 1024, 1024, 0);

  // 3. prop_feature -> cat[512:1536]
  bmp_kernel<<<dim3(64, BB), 256, 0, stream>>>(feat_lr, segments, cat, 1024, 64, CAT_C, 512);

  // 4. prop_roi -> cat[0:512]
  bmp_kernel<<<dim3(64, BB), 256, 0, stream>>>(frame_feat, frame_segs, tmpA, 512, 256, 512, 0);
  pw_gemm_kernel<<<dim3(32, BB), blk, 0, stream>>>(tmpA, w_roi, b_roi, tmpB, 512, 512);
  gn_relu_kernel<<<BB * GROUPS, 256, 0, stream>>>(tmpB, g_roi, be_roi, cat, 512, CAT_C, 0);

  // 5. con_feature: gather(feat_lr) + MFMA GEMM -> cat[2546:3058]
  gather_kernel<16, 64, 64, 1024><<<dim3(16, BB), 256, 0, stream>>>(feat_lr, anchor, G1);
  anchor_mfma_kernel<<<dim3(8, BB, 4), 256, 0, stream>>>(G1, Wb1, P1, 16384, 4096);
  anchor_reduce_kernel<<<1024, 256, 0, stream>>>(P1, 4, b_cp, anchor, 64, cat, CAT_C, 2546);

  // 6. frame_con: gather(frame_feat) + MFMA GEMM -> tmpA; then prop_con -> cat[3058:3570]
  gather_kernel<8, 256, 16, 512><<<dim3(32, BB), 256, 0, stream>>>(frame_feat, frame_anchor, G0);
  anchor_mfma_kernel<<<dim3(8, BB, 2), 256, 0, stream>>>(G0, Wb0, P0, 4096, 2048);
  anchor_reduce_kernel<<<1024, 256, 0, stream>>>(P0, 2, b_cp0, frame_anchor, 256, tmpA, 512, 0);
  pw_gemm_kernel<<<dim3(32, BB), blk, 0, stream>>>(tmpA, w_roi, b_roi, tmpB, 512, 512);
  gn_relu_kernel<<<BB * GROUPS, 256, 0, stream>>>(tmpB, g_roi, be_roi, cat, 512, CAT_C, 3058);

  // 7. copies
  copy_to_cat_kernel<<<(BB * 498 * 64 + 255) / 256, 256, 0, stream>>>(feat_lastcls, cat, 498, 2048);
  copy_to_cat_kernel<<<(BB * 2 * 64 + 255) / 256, 256, 0, stream>>>(locres, cat, 2, 3570);

  // 8. final projection
  pw_gemm_kernel<<<dim3(32, BB), blk, 0, stream>>>(cat, w_prop, b_prop, tmpA, CAT_C, 512);
  gn_relu_kernel<<<BB * GROUPS, 256, 0, stream>>>(tmpA, g_prop, be_prop, out_main, 512, 512, 0);
}

// Round 3
// 442.374 us; speedup vs baseline: 4.1062x; 2.0022x over previous
//
#include <hip/hip_runtime.h>
#include <math.h>

#define BB 8
#define CATP 3584   // padded cat K (3572 -> 3584, zeros)
#define CAT_REAL 3572

typedef __attribute__((ext_vector_type(8))) short short8;
typedef __attribute__((ext_vector_type(4))) float f32x4;

__device__ inline ushort f2bf(float f) {
  union { float f; unsigned u; } x;
  x.f = f;
  return (ushort)((x.u + 0x7FFFu + ((x.u >> 16) & 1u)) >> 16);
}

// ---------------------------------------------------------------------------
// f32 -> bf16 elementwise convert (4-wide), n multiple of 4
// ---------------------------------------------------------------------------
__global__ __launch_bounds__(256) void cvt_bf16_kernel(
    const float4* __restrict__ X, uint2* __restrict__ Y, int n4) {
  const int i = blockIdx.x * 256 + threadIdx.x;
  if (i >= n4) return;
  const float4 v = X[i];
  uint2 o;
  o.x = (unsigned)f2bf(v.x) | ((unsigned)f2bf(v.y) << 16);
  o.y = (unsigned)f2bf(v.z) | ((unsigned)f2bf(v.w) << 16);
  Y[i] = o;
}

// w_prop [512][3572] f32 -> [512][3584] bf16 with zero pad
__global__ __launch_bounds__(256) void cvt_pad_wprop_kernel(
    const float* __restrict__ W, unsigned* __restrict__ Y) {
  const int idx = blockIdx.x * 256 + threadIdx.x;
  if (idx >= 512 * (CATP / 2)) return;
  const int p = idx % (CATP / 2);
  const int o = idx / (CATP / 2);
  const int c0 = p * 2;
  unsigned pk = 0;
  if (c0 < CAT_REAL) {
    const float* w = W + (size_t)o * CAT_REAL + c0;
    pk = (unsigned)f2bf(w[0]) | ((unsigned)f2bf(w[1]) << 16);
  }
  Y[(size_t)o * (CATP / 2) + p] = pk;
}

// ---------------------------------------------------------------------------
// Transpose+convert: X f32 [B][C][64] -> Y bf16 rows (b*64+t)*rowStride+chOff+c
// grid (ceil(C/64), B)
// ---------------------------------------------------------------------------
__global__ __launch_bounds__(256) void transpose_cvt_kernel(
    const float* __restrict__ X, ushort* __restrict__ Y, int C, int rowStride,
    int chOff) {
  __shared__ float tile[64 * 65];
  const int c0 = blockIdx.x * 64;
  const int b = blockIdx.y;
  for (int e = threadIdx.x; e < 4096; e += 256) {
    const int cc = e >> 6, t = e & 63;
    const int c = c0 + cc;
    tile[cc * 65 + t] = (c < C) ? X[((size_t)b * C + c) * 64 + t] : 0.f;
  }
  __syncthreads();
  for (int e = threadIdx.x; e < 4096; e += 256) {
    const int t = e >> 6, cc = e & 63;
    const int c = c0 + cc;
    if (c < C)
      Y[((size_t)(b * 64) + t) * rowStride + chOff + c] = f2bf(tile[cc * 65 + t]);
  }
}

// LocResult [8][2][64] -> cat[3570:3572], plus zero-pad cat[3572:3584]
__global__ __launch_bounds__(256) void locres_pad_kernel(
    const float* __restrict__ L, ushort* __restrict__ cat) {
  const int idx = blockIdx.x * 256 + threadIdx.x;
  if (idx >= BB * 64 * 14) return;
  const int j = idx % 14;
  const int t = (idx / 14) % 64;
  const int b = idx / (14 * 64);
  const ushort v = (j < 2) ? f2bf(L[((size_t)b * 2 + j) * 64 + t]) : (ushort)0;
  cat[((size_t)(b * 64) + t) * CATP + 3570 + j] = v;
}

// ---------------------------------------------------------------------------
// BoundaryMaxPooling -> bf16 transposed rows
// ---------------------------------------------------------------------------
__global__ __launch_bounds__(256) void bmp_kernel(
    const float* __restrict__ F, const int* __restrict__ segs,
    ushort* __restrict__ Y, int C, int L, int rowStride, int chOff) {
  const int t = blockIdx.x;
  const int b = blockIdx.y;
  const int* sg = segs + ((size_t)b * 64 + t) * 4;
  const int s0 = min(max(sg[0], 0), L - 1);
  const int e0 = max(min(max(sg[1], 0), L - 1), s0);
  const int s1 = min(max(sg[2], 0), L - 1);
  const int e1 = max(min(max(sg[3], 0), L - 1), s1);
  const int C2 = C >> 1;
  for (int c = threadIdx.x; c < C; c += 256) {
    const int s = (c < C2) ? s0 : s1;
    const int e = (c < C2) ? e0 : e1;
    const float* row = F + ((size_t)b * C + c) * L;
    float m = -INFINITY;
    for (int l = s; l <= e; l++) m = fmaxf(m, row[l]);
    Y[((size_t)(b * 64) + t) * rowStride + chOff + c] = f2bf(m);
  }
}

// ---------------------------------------------------------------------------
// Fused bf16 MFMA GEMM + GroupNorm + ReLU.
// Y_raw[o][b,t] = bias[o] + sum_c Wb[o][c] * Xt[b*64+t][c]
// Block: (64 o) x (64 t, one b); 4 waves split K; LDS reduce; in-block GN
// (block owns whole groups: cpg in {16,32}); writes f32 [b][M][64] and/or
// bf16 cat rows. grid (M/64, B).
// ---------------------------------------------------------------------------
__global__ __launch_bounds__(256) void gemm_gn_relu_kernel(
    const ushort* __restrict__ Xt, const ushort* __restrict__ Wb,
    const float* __restrict__ bias, const float* __restrict__ gamma,
    const float* __restrict__ beta, int Kp, int M, int cpgShift,
    float* __restrict__ outF, ushort* __restrict__ catOut, int chOff) {
  const int o0 = blockIdx.x * 64;
  const int b = blockIdx.y;
  const int w = threadIdx.x >> 6;
  const int lane = threadIdx.x & 63;
  const int l15 = lane & 15, l4 = lane >> 4;
  const int wk = Kp >> 2;
  const int kbeg = w * wk, kend = kbeg + wk;

  f32x4 acc[4][4] = {};
  const ushort* ap[4];
  const ushort* bp[4];
#pragma unroll
  for (int i = 0; i < 4; i++)
    ap[i] = Wb + (size_t)(o0 + i * 16 + l15) * Kp + l4 * 8;
#pragma unroll
  for (int j = 0; j < 4; j++)
    bp[j] = Xt + (size_t)(b * 64 + j * 16 + l15) * Kp + l4 * 8;

  for (int k = kbeg; k < kend; k += 32) {
    short8 a[4], x[4];
#pragma unroll
    for (int i = 0; i < 4; i++) a[i] = *(const short8*)(ap[i] + k);
#pragma unroll
    for (int j = 0; j < 4; j++) x[j] = *(const short8*)(bp[j] + k);
#pragma unroll
    for (int i = 0; i < 4; i++)
#pragma unroll
      for (int j = 0; j < 4; j++)
        acc[i][j] = __builtin_amdgcn_mfma_f32_16x16x32_bf16(a[i], x[j],
                                                            acc[i][j], 0, 0, 0);
  }

  __shared__ float red[64 * 65];
  for (int ww = 0; ww < 4; ww++) {
    __syncthreads();
    if (w == ww) {
#pragma unroll
      for (int i = 0; i < 4; i++)
#pragma unroll
        for (int j = 0; j < 4; j++)
#pragma unroll
          for (int r = 0; r < 4; r++) {
            const int m = i * 16 + l4 * 4 + r;
            const int n = j * 16 + l15;
            if (ww == 0)
              red[m * 65 + n] = acc[i][j][r] + bias[o0 + m];
            else
              red[m * 65 + n] += acc[i][j][r];
          }
    }
  }
  __syncthreads();

  // GroupNorm stats (groups fully contained in this block)
  const int cpg = 1 << cpgShift;
  const int ngroups = 64 >> cpgShift;
  __shared__ float rs[4], rss[4], gmean[4], grstd[4];
  for (int gi = 0; gi < ngroups; gi++) {
    float s = 0.f, ss = 0.f;
    const int nel = cpg << 6;
    for (int e = threadIdx.x; e < nel; e += 256) {
      const float v = red[((gi << cpgShift) + (e >> 6)) * 65 + (e & 63)];
      s += v;
      ss += v * v;
    }
#pragma unroll
    for (int off = 32; off > 0; off >>= 1) {
      s += __shfl_down(s, off);
      ss += __shfl_down(ss, off);
    }
    if (lane == 0) { rs[w] = s; rss[w] = ss; }
    __syncthreads();
    if (threadIdx.x == 0) {
      const float ts = rs[0] + rs[1] + rs[2] + rs[3];
      const float tss = rss[0] + rss[1] + rss[2] + rss[3];
      const float mean = ts / (float)nel;
      const float var = tss / (float)nel - mean * mean;
      gmean[gi] = mean;
      grstd[gi] = rsqrtf(var + 1e-5f);
    }
    __syncthreads();
  }

  if (outF) {
    for (int e = threadIdx.x; e < 4096; e += 256) {
      const int m = e >> 6, n = e & 63;
      const int gi = m >> cpgShift;
      const int c = o0 + m;
      float v = (red[m * 65 + n] - gmean[gi]) * grstd[gi] * gamma[c] + beta[c];
      v = fmaxf(v, 0.f);
      outF[((size_t)b * M + c) * 64 + n] = v;
    }
  }
  if (catOut) {
    for (int e = threadIdx.x; e < 4096; e += 256) {
      const int n = e >> 6, m = e & 63;
      const int gi = m >> cpgShift;
      const int c = o0 + m;
      float v = (red[m * 65 + n] - gmean[gi]) * grstd[gi] * gamma[c] + beta[c];
      v = fmaxf(v, 0.f);
      catOut[((size_t)(b * 64) + n) * CATP + chOff + c] = f2bf(v);
    }
  }
}

// ---------------------------------------------------------------------------
// Anchor gather: G[b][t][c*K+k] = bf16(F[b][c][idx(b,t,k)])
// ---------------------------------------------------------------------------
template <int K, int L, int CC, int Cin>
__global__ __launch_bounds__(256) void gather_kernel(
    const float* __restrict__ F, const int* __restrict__ anc,
    ushort* __restrict__ G) {
  __shared__ float Fl[CC * L];
  __shared__ int sidx[64 * K];
  const int c0 = blockIdx.x * CC;
  const int b = blockIdx.y;
  const int tid = threadIdx.x;
  for (int e = tid; e < 64 * K; e += 256) {
    const int tt = e / K, k = e % K;
    const int a0 = anc[((size_t)b * 64 + tt) * 2 + 0];
    const int a1 = anc[((size_t)b * 64 + tt) * 2 + 1];
    const int left = min(max(a0, 0), L);
    const int right = min(max(a1, 0), L);
    const int seglen = right + 1 - left;
    sidx[e] = min(max(left + (k * seglen) / K, 0), L - 1);
  }
  const float* Fb = F + ((size_t)b * Cin + c0) * L;
  for (int e = tid; e < CC * L; e += 256) Fl[e] = Fb[e];
  __syncthreads();
  constexpr int KK = Cin * K;
  constexpr int PH = (CC * K) / 2;
  for (int f = tid; f < 64 * PH; f += 256) {
    const int t = f / PH;
    const int p = f % PH;
    const int col0 = 2 * p;
    const int cc = col0 / K;
    const int k = col0 % K;
    const float v0 = Fl[cc * L + sidx[t * K + k]];
    const float v1 = Fl[cc * L + sidx[t * K + k + 1]];
    const unsigned pk = (unsigned)f2bf(v0) | ((unsigned)f2bf(v1) << 16);
    *(unsigned*)(G + (size_t)(b * 64 + t) * KK + c0 * K + col0) = pk;
  }
}

// ---------------------------------------------------------------------------
// MFMA GEMM for anchor conv: P[kz][b][n][m] partials (split-K)
// ---------------------------------------------------------------------------
__global__ __launch_bounds__(256) void anchor_mfma_kernel(
    const ushort* __restrict__ G, const ushort* __restrict__ Wb,
    float* __restrict__ P, int KK, int kspan) {
  const int n0 = blockIdx.x * 64;
  const int b = blockIdx.y;
  const int kz = blockIdx.z;
  const int w = threadIdx.x >> 6;
  const int lane = threadIdx.x & 63;
  const int l15 = lane & 15, l4 = lane >> 4;
  const int wk = kspan >> 2;
  const int kbeg = kz * kspan + w * wk;
  const int kend = kbeg + wk;

  f32x4 acc[4][4] = {};
  const ushort* ap[4];
  const ushort* bp[4];
#pragma unroll
  for (int i = 0; i < 4; i++)
    ap[i] = G + ((size_t)b * 64 + i * 16 + l15) * KK + l4 * 8;
#pragma unroll
  for (int j = 0; j < 4; j++)
    bp[j] = Wb + (size_t)(n0 + j * 16 + l15) * KK + l4 * 8;

  for (int k = kbeg; k < kend; k += 32) {
    short8 a[4], bb[4];
#pragma unroll
    for (int i = 0; i < 4; i++) a[i] = *(const short8*)(ap[i] + k);
#pragma unroll
    for (int j = 0; j < 4; j++) bb[j] = *(const short8*)(bp[j] + k);
#pragma unroll
    for (int i = 0; i < 4; i++)
#pragma unroll
      for (int j = 0; j < 4; j++)
        acc[i][j] = __builtin_amdgcn_mfma_f32_16x16x32_bf16(a[i], bb[j],
                                                            acc[i][j], 0, 0, 0);
  }

  __shared__ float red[64 * 65];
  for (int ww = 0; ww < 4; ww++) {
    __syncthreads();
    if (w == ww) {
#pragma unroll
      for (int i = 0; i < 4; i++)
#pragma unroll
        for (int j = 0; j < 4; j++)
#pragma unroll
          for (int r = 0; r < 4; r++) {
            const int m = i * 16 + l4 * 4 + r;
            const int n = j * 16 + l15;
            if (ww == 0)
              red[m * 65 + n] = acc[i][j][r];
            else
              red[m * 65 + n] += acc[i][j][r];
          }
    }
  }
  __syncthreads();
  float* Pp = P + (((size_t)kz * BB + b) * 512 + n0) * 64;
  for (int e = threadIdx.x; e < 4096; e += 256) {
    const int n = e >> 6, m = e & 63;
    Pp[e] = red[m * 65 + n];
  }
}

// ---------------------------------------------------------------------------
// Split-K reduce + valid mask + bias -> bf16 transposed rows (via LDS tile)
// grid (512/64, B)
// ---------------------------------------------------------------------------
__global__ __launch_bounds__(256) void anchor_reduce_kernel(
    const float* __restrict__ P, int ks, const float* __restrict__ bias,
    const int* __restrict__ anc, int L, ushort* __restrict__ Y, int rowStride,
    int chOff) {
  __shared__ float tile[64 * 65];
  __shared__ float sval[64];
  const int o0 = blockIdx.x * 64;
  const int b = blockIdx.y;
  if (threadIdx.x < 64) {
    const int t = threadIdx.x;
    const int a0 = anc[((size_t)b * 64 + t) * 2 + 0];
    const int a1 = anc[((size_t)b * 64 + t) * 2 + 1];
    const int left = min(max(a0, 0), L);
    const int right = min(max(a1, 0), L);
    sval[t] = (right > left) ? 1.f : 0.f;
  }
  __syncthreads();
  for (int e = threadIdx.x; e < 4096; e += 256) {
    const int nl = e >> 6, m = e & 63;
    const int n = o0 + nl;
    float s = 0.f;
    for (int z = 0; z < ks; z++)
      s += P[(((size_t)z * BB + b) * 512 + n) * 64 + m];
    tile[nl * 65 + m] = s * sval[m] + bias[n];
  }
  __syncthreads();
  for (int e = threadIdx.x; e < 4096; e += 256) {
    const int m = e >> 6, nl = e & 63;
    Y[((size_t)(b * 64) + m) * rowStride + chOff + o0 + nl] =
        f2bf(tile[nl * 65 + m]);
  }
}

extern "C" void kernel_launch(void* const* d_in, const int* in_sizes, int n_in,
                              void* d_out, int out_size, void* d_ws,
                              size_t ws_size, hipStream_t stream) {
  const float* feature      = (const float*)d_in[0];
  const float* frame_feat   = (const float*)d_in[1];
  const int*   segments     = (const int*)d_in[2];
  const int*   frame_segs   = (const int*)d_in[3];
  const float* feat_lastcls = (const float*)d_in[4];
  const int*   anchor       = (const int*)d_in[5];
  const int*   frame_anchor = (const int*)d_in[6];
  const float* locres       = (const float*)d_in[8];
  const float* w_cur  = (const float*)d_in[9];
  const float* b_cur  = (const float*)d_in[10];
  const float* g_cur  = (const float*)d_in[11];
  const float* be_cur = (const float*)d_in[12];
  const float* w_lr   = (const float*)d_in[13];
  const float* b_lr   = (const float*)d_in[14];
  const float* g_lr   = (const float*)d_in[15];
  const float* be_lr  = (const float*)d_in[16];
  const float* w_roi  = (const float*)d_in[17];
  const float* b_roi  = (const float*)d_in[18];
  const float* g_roi  = (const float*)d_in[19];
  const float* be_roi = (const float*)d_in[20];
  const float* w_cp   = (const float*)d_in[21];  // [512,1024,16]
  const float* b_cp   = (const float*)d_in[22];
  const float* w_cp0  = (const float*)d_in[23];  // [512,512,8]
  const float* b_cp0  = (const float*)d_in[24];
  const float* w_prop = (const float*)d_in[25];  // [512,3572]
  const float* b_prop = (const float*)d_in[26];
  const float* g_prop = (const float*)d_in[27];
  const float* be_prop= (const float*)d_in[28];

  float* out_main = (float*)d_out;                  // [8,512,64]
  float* feat_lr  = (float*)d_out + BB * 512 * 64;  // [8,1024,64]

  // workspace layout (ushort elements first, then f32 partials)
  ushort* cat_t = (ushort*)d_ws;            // [8*64][3584] = 1,835,008
  ushort* Ft    = cat_t + 1835008;          // [8*64][512]  = 262,144
  ushort* XbmpT = Ft + 262144;              // 262,144
  ushort* FconT = XbmpT + 262144;           // 262,144
  ushort* Wcur  = FconT + 262144;           // 262,144
  ushort* Wlr   = Wcur + 262144;            // 524,288
  ushort* Wroi  = Wlr + 524288;             // 262,144
  ushort* Wprop = Wroi + 262144;            // 1,835,008
  ushort* Wcp   = Wprop + 1835008;          // 8,388,608
  ushort* Wcp0  = Wcp + 8388608;            // 2,097,152
  ushort* G1    = Wcp0 + 2097152;           // 8,388,608
  ushort* G0    = G1 + 8388608;             // 2,097,152
  float*  P1    = (float*)(G0 + 2097152);   // 1,048,576 f
  float*  P0    = P1 + 1048576;             // 524,288 f
  // total ~56 MB

  // --- weight conversions ---
  cvt_bf16_kernel<<<8192, 256, 0, stream>>>((const float4*)w_cp, (uint2*)Wcp, 2097152);
  cvt_bf16_kernel<<<2048, 256, 0, stream>>>((const float4*)w_cp0, (uint2*)Wcp0, 524288);
  cvt_bf16_kernel<<<256, 256, 0, stream>>>((const float4*)w_cur, (uint2*)Wcur, 65536);
  cvt_bf16_kernel<<<512, 256, 0, stream>>>((const float4*)w_lr, (uint2*)Wlr, 131072);
  cvt_bf16_kernel<<<256, 256, 0, stream>>>((const float4*)w_roi, (uint2*)Wroi, 65536);
  cvt_pad_wprop_kernel<<<3584, 256, 0, stream>>>(w_prop, (unsigned*)Wprop);

  // --- activation transpose: feature -> Ft ---
  transpose_cvt_kernel<<<dim3(8, BB), 256, 0, stream>>>(feature, Ft, 512, 512, 0);

  // 1. fm_short -> cat[1536:2048]
  gemm_gn_relu_kernel<<<dim3(8, BB), 256, 0, stream>>>(
      Ft, Wcur, b_cur, g_cur, be_cur, 512, 512, 4, nullptr, cat_t, 1536);

  // 2. feat_lr (output #2, f32)
  gemm_gn_relu_kernel<<<dim3(16, BB), 256, 0, stream>>>(
      Ft, Wlr, b_lr, g_lr, be_lr, 512, 1024, 5, feat_lr, nullptr, 0);

  // 3. prop_feature -> cat[512:1536]
  bmp_kernel<<<dim3(64, BB), 256, 0, stream>>>(feat_lr, segments, cat_t, 1024, 64, CATP, 512);

  // 4. prop_roi: bmp(frame_feat) -> XbmpT; GEMM+GN -> cat[0:512]
  bmp_kernel<<<dim3(64, BB), 256, 0, stream>>>(frame_feat, frame_segs, XbmpT, 512, 256, 512, 0);
  gemm_gn_relu_kernel<<<dim3(8, BB), 256, 0, stream>>>(
      XbmpT, Wroi, b_roi, g_roi, be_roi, 512, 512, 4, nullptr, cat_t, 0);

  // 5. con_feature -> cat[2546:3058]
  gather_kernel<16, 64, 64, 1024><<<dim3(16, BB), 256, 0, stream>>>(feat_lr, anchor, G1);
  anchor_mfma_kernel<<<dim3(8, BB, 4), 256, 0, stream>>>(G1, Wcp, P1, 16384, 4096);
  anchor_reduce_kernel<<<dim3(8, BB), 256, 0, stream>>>(P1, 4, b_cp, anchor, 64, cat_t, CATP, 2546);

  // 6. frame_con -> FconT; prop_con -> cat[3058:3570]
  gather_kernel<8, 256, 16, 512><<<dim3(32, BB), 256, 0, stream>>>(frame_feat, frame_anchor, G0);
  anchor_mfma_kernel<<<dim3(8, BB, 2), 256, 0, stream>>>(G0, Wcp0, P0, 4096, 2048);
  anchor_reduce_kernel<<<dim3(8, BB), 256, 0, stream>>>(P0, 2, b_cp0, frame_anchor, 256, FconT, 512, 0);
  gemm_gn_relu_kernel<<<dim3(8, BB), 256, 0, stream>>>(
      FconT, Wroi, b_roi, g_roi, be_roi, 512, 512, 4, nullptr, cat_t, 3058);

  // 7. feature_lastclass -> cat[2048:2546]; LocResult+pad -> cat[3570:3584]
  transpose_cvt_kernel<<<dim3(8, BB), 256, 0, stream>>>(feat_lastcls, cat_t, 498, CATP, 2048);
  locres_pad_kernel<<<28, 256, 0, stream>>>(locres, cat_t);

  // 8. final projection -> out_main (f32)
  gemm_gn_relu_kernel<<<dim3(8, BB), 256, 0, stream>>>(
      cat_t, Wprop, b_prop, g_prop, be_prop, CATP, 512, 4, out_main, nullptr, 0);
}